// Round 8
// baseline (159.290 us; speedup 1.0000x reference)
//
#include <hip/hip_runtime.h>
#include <hip/hip_bf16.h>

// ---------------------------------------------------------------------------
// QuixerCore: 10-qubit QSVT/LCU quantum circuit simulator.
// R3: phased-LDS PQC (gates only on register bits; 8 LDS layout remaps).
// R4: register-tiled params GEMM.   R5: packed-fp32 v2f gate math.
// R6: product-state init for step1. R7: angle prefetch above remaps.
// R8: (a) dual-token step waves: two states packed as float4 in ONE slab,
//     b128 remaps -> one lgkmcnt drain per phase for TWO tokens, 2x gate ILP;
//     (b) step2 loads shared input once; (c) final measurement reductions via
//     LDS transpose (30 lanes x 64 sums) instead of 60 serial shuffle chains.
// Canonical layout: n = r*64+lane, wire w at bit 9-w.
// P2 layout: lane bits 0..5 = wires 5,4,6,7,2,3 ; reg bits 6..9 = wires 8,9,0,1.
// P8 layout: wire->bit: w0=1, w1=0, w>=2: bit w.
// ---------------------------------------------------------------------------

#define NQ   10
#define NT   32
#define DM   512
#define BATCH 128
#define NPQC 40
#define DIM  1024
#define NROWS (BATCH * NT)    // 4096
#define PSTRIDE (BATCH * DIM) // elements per partial slice (v2f)

typedef float v2f __attribute__((ext_vector_type(2)));
typedef float v4f __attribute__((ext_vector_type(4)));

__device__ __forceinline__ v2f Jrot(v2f v) {   // (v.y, -v.x)
  return __builtin_shufflevector(v, -v, 1, 2);
}
__device__ __forceinline__ v2f Jc(v2f v) {     // (-v.y, v.x)
  return __builtin_shufflevector(-v, v, 1, 2);
}

// ------------------------- gate primitives ---------------------------------

template<int B>
__device__ __forceinline__ void g_ry(v2f (&a)[16], float c, float s) {
  static_assert(B >= 6, "RY targets must be register bits");
  constexpr int m = 1 << (B - 6);
#pragma unroll
  for (int r = 0; r < 16; ++r) {
    if (!(r & m)) {
      int r1 = r | m;
      v2f a0 = a[r], a1 = a[r1];
      a[r]  = c * a0 - s * a1;
      a[r1] = s * a0 + c * a1;
    }
  }
}

template<int BC, int BT>
__device__ __forceinline__ void g_crx(v2f (&a)[16], int lane, float c, float s) {
  static_assert(BT >= 6, "CRX targets must be register bits");
  constexpr int m = 1 << (BT - 6);
  bool lane_ok = (BC >= 6) || ((lane >> BC) & 1);
  float ce = lane_ok ? c : 1.f;
  float se = lane_ok ? s : 0.f;
#pragma unroll
  for (int r = 0; r < 16; ++r) {
    if (!(r & m)) {
      if constexpr (BC >= 6) { if (!((r >> (BC - 6)) & 1)) continue; }
      int r1 = r | m;
      v2f a0 = a[r], a1 = a[r1];
      a[r]  = ce * a0 + se * Jrot(a1);
      a[r1] = ce * a1 + se * Jrot(a0);
    }
  }
}

// ------------------------- layout remaps -----------------------------------
// Single-state (v2f slab) — used by final_kernel.
template<int L0, int L1, int L2, int L3>
__device__ __forceinline__ void remap(v2f (&a)[16], v2f* __restrict__ slab,
                                      int lane) {
  constexpr int LM = (1 << L0) | (1 << L1) | (1 << L2) | (1 << L3);
#pragma unroll
  for (int r = 0; r < 16; ++r) {
    int f = 0;
    if (L0 < 4 && (r & 1)) f |= 1 << L0;
    if (L1 < 4 && (r & 2)) f |= 1 << L1;
    if (L2 < 4 && (r & 4)) f |= 1 << L2;
    if (L3 < 4 && (r & 8)) f |= 1 << L3;
    slab[r * 64 + (lane ^ f)] = a[r];
  }
  asm volatile("s_waitcnt lgkmcnt(0)" ::: "memory");
  int la = lane & ~LM & 63;
  la |= ((lane >> L0) & 1) << 6;
  la |= ((lane >> L1) & 1) << 7;
  la |= ((lane >> L2) & 1) << 8;
  la |= ((lane >> L3) & 1) << 9;
  if (L0 < 4) la |= ((lane >> L0) & 1) << L0;
  if (L1 < 4) la |= ((lane >> L1) & 1) << L1;
  if (L2 < 4) la |= ((lane >> L2) & 1) << L2;
  if (L3 < 4) la |= ((lane >> L3) & 1) << L3;
#pragma unroll
  for (int r = 0; r < 16; ++r) {
    int rc = ((r & 1) ? (1 << L0) : 0) | ((r & 2) ? (1 << L1) : 0)
           | ((r & 4) ? (1 << L2) : 0) | ((r & 8) ? (1 << L3) : 0);
    a[r] = slab[la ^ rc];
  }
}

// Dual-state (v4f slab: {A.re,A.im,B.re,B.im}) — used by pqc_step.
// One drain moves BOTH states; b128 DS ops halve instruction count.
template<int L0, int L1, int L2, int L3>
__device__ __forceinline__ void remap2(v2f (&a)[16], v2f (&b)[16],
                                       v4f* __restrict__ slab, int lane) {
  constexpr int LM = (1 << L0) | (1 << L1) | (1 << L2) | (1 << L3);
#pragma unroll
  for (int r = 0; r < 16; ++r) {
    int f = 0;
    if (L0 < 4 && (r & 1)) f |= 1 << L0;
    if (L1 < 4 && (r & 2)) f |= 1 << L1;
    if (L2 < 4 && (r & 4)) f |= 1 << L2;
    if (L3 < 4 && (r & 8)) f |= 1 << L3;
    v4f pk;
    pk.x = a[r].x; pk.y = a[r].y; pk.z = b[r].x; pk.w = b[r].y;
    slab[r * 64 + (lane ^ f)] = pk;
  }
  asm volatile("s_waitcnt lgkmcnt(0)" ::: "memory");
  int la = lane & ~LM & 63;
  la |= ((lane >> L0) & 1) << 6;
  la |= ((lane >> L1) & 1) << 7;
  la |= ((lane >> L2) & 1) << 8;
  la |= ((lane >> L3) & 1) << 9;
  if (L0 < 4) la |= ((lane >> L0) & 1) << L0;
  if (L1 < 4) la |= ((lane >> L1) & 1) << L1;
  if (L2 < 4) la |= ((lane >> L2) & 1) << L2;
  if (L3 < 4) la |= ((lane >> L3) & 1) << L3;
#pragma unroll
  for (int r = 0; r < 16; ++r) {
    int rc = ((r & 1) ? (1 << L0) : 0) | ((r & 2) ? (1 << L1) : 0)
           | ((r & 4) ? (1 << L2) : 0) | ((r & 8) ? (1 << L3) : 0);
    v4f v = slab[la ^ rc];
    a[r].x = v.x; a[r].y = v.y;
    b[r].x = v.z; b[r].y = v.w;
  }
}

// ------------------------- phased PQC: single (final) ----------------------
__device__ __forceinline__ void apply_pqc_phased(v2f (&a)[16],
    const float2* __restrict__ cs, v2f* __restrict__ slab, int lane) {
#define RYt(B, t)      g_ry<B>(a, t.x, t.y);
#define CXt(BC, BT, t) g_crx<BC, BT>(a, lane, t.x, t.y);
  float2 t10 = cs[10], t11 = cs[11], t12 = cs[12];
  float2 t0 = cs[0], t1 = cs[1], t2 = cs[2], t3 = cs[3];
  float2 t4 = cs[4], t5 = cs[5], t6 = cs[6], t7 = cs[7];
  float2 t8 = cs[8], t9 = cs[9];
  RYt(9,t0) RYt(8,t1) RYt(7,t2) RYt(6,t3)
  remap<5,4,3,2>(a, slab, lane);
  RYt(6,t4) RYt(7,t5) RYt(8,t6) RYt(9,t7)
  remap<1,0,2,3>(a, slab, lane);
  RYt(6,t8) RYt(7,t9)
  CXt(7,8,t10) CXt(6,7,t11) CXt(3,6,t12)
  float2 t13 = cs[13], t14 = cs[14], t15 = cs[15], t16 = cs[16];
  remap<1,0,2,3>(a, slab, lane);
  CXt(8,9,t13) CXt(7,8,t14) CXt(6,7,t15) CXt(5,6,t16)
  float2 t17 = cs[17], t18 = cs[18], t19 = cs[19];
  float2 t20 = cs[20], t21 = cs[21], t22 = cs[22], t23 = cs[23];
  remap<2,3,4,5>(a, slab, lane);
  CXt(8,9,t17) CXt(7,8,t18) CXt(6,7,t19)
  RYt(6,t20) RYt(7,t21) RYt(8,t22) RYt(9,t23)
  float2 t24 = cs[24], t25 = cs[25], t26 = cs[26], t27 = cs[27];
  remap<2,3,4,5>(a, slab, lane);
  RYt(6,t24) RYt(7,t25) RYt(8,t26) RYt(9,t27)
  float2 t28 = cs[28], t29 = cs[29];
  float2 t30 = cs[30], t31 = cs[31], t32 = cs[32], t33 = cs[33];
  remap<1,0,2,3>(a, slab, lane);
  RYt(6,t28) RYt(7,t29)
  CXt(7,6,t30) CXt(8,7,t31) CXt(9,8,t32) CXt(4,9,t33)
  float2 t34 = cs[34], t35 = cs[35], t36 = cs[36], t37 = cs[37];
  remap<4,5,1,0>(a, slab, lane);
  CXt(7,6,t34) CXt(8,7,t35) CXt(9,8,t36) CXt(2,9,t37)
  float2 t38 = cs[38], t39 = cs[39];
  remap<2,3,4,5>(a, slab, lane);
  CXt(7,6,t38) CXt(8,7,t39)
#undef RYt
#undef CXt
}

// ------------------------- phased PQC: dual (steps) ------------------------
// SKIP_HEAD: caller pre-built both states in P2 layout (product of 10 RYs).
template<bool SKIP_HEAD>
__device__ __forceinline__ void apply_pqc2(v2f (&A)[16], v2f (&B)[16],
    const float2* __restrict__ pA, const float2* __restrict__ pB,
    v4f* __restrict__ slab, int lane) {
#define RY2(B_, u, v)      g_ry<B_>(A, u.x, u.y); g_ry<B_>(B, v.x, v.y);
#define CX2(BC, BT, u, v)  g_crx<BC,BT>(A, lane, u.x, u.y); g_crx<BC,BT>(B, lane, v.x, v.y);
  float2 uA10 = pA[10], uA11 = pA[11], uA12 = pA[12];
  float2 uB10 = pB[10], uB11 = pB[11], uB12 = pB[12];
  if constexpr (!SKIP_HEAD) {
    float2 a0=pA[0],a1=pA[1],a2=pA[2],a3=pA[3],a4=pA[4];
    float2 a5=pA[5],a6=pA[6],a7=pA[7],a8=pA[8],a9=pA[9];
    float2 b0=pB[0],b1=pB[1],b2=pB[2],b3=pB[3],b4=pB[4];
    float2 b5=pB[5],b6=pB[6],b7=pB[7],b8=pB[8],b9=pB[9];
    RY2(9,a0,b0) RY2(8,a1,b1) RY2(7,a2,b2) RY2(6,a3,b3)
    remap2<5,4,3,2>(A, B, slab, lane);
    RY2(6,a4,b4) RY2(7,a5,b5) RY2(8,a6,b6) RY2(9,a7,b7)
    remap2<1,0,2,3>(A, B, slab, lane);
    RY2(6,a8,b8) RY2(7,a9,b9)
  }
  CX2(7,8,uA10,uB10) CX2(6,7,uA11,uB11) CX2(3,6,uA12,uB12)
  float2 uA13=pA[13],uA14=pA[14],uA15=pA[15],uA16=pA[16];
  float2 uB13=pB[13],uB14=pB[14],uB15=pB[15],uB16=pB[16];
  remap2<1,0,2,3>(A, B, slab, lane);
  CX2(8,9,uA13,uB13) CX2(7,8,uA14,uB14) CX2(6,7,uA15,uB15) CX2(5,6,uA16,uB16)
  float2 uA17=pA[17],uA18=pA[18],uA19=pA[19];
  float2 uB17=pB[17],uB18=pB[18],uB19=pB[19];
  float2 uA20=pA[20],uA21=pA[21],uA22=pA[22],uA23=pA[23];
  float2 uB20=pB[20],uB21=pB[21],uB22=pB[22],uB23=pB[23];
  remap2<2,3,4,5>(A, B, slab, lane);
  CX2(8,9,uA17,uB17) CX2(7,8,uA18,uB18) CX2(6,7,uA19,uB19)
  RY2(6,uA20,uB20) RY2(7,uA21,uB21) RY2(8,uA22,uB22) RY2(9,uA23,uB23)
  float2 uA24=pA[24],uA25=pA[25],uA26=pA[26],uA27=pA[27];
  float2 uB24=pB[24],uB25=pB[25],uB26=pB[26],uB27=pB[27];
  remap2<2,3,4,5>(A, B, slab, lane);
  RY2(6,uA24,uB24) RY2(7,uA25,uB25) RY2(8,uA26,uB26) RY2(9,uA27,uB27)
  float2 uA28=pA[28],uA29=pA[29];
  float2 uB28=pB[28],uB29=pB[29];
  float2 uA30=pA[30],uA31=pA[31],uA32=pA[32],uA33=pA[33];
  float2 uB30=pB[30],uB31=pB[31],uB32=pB[32],uB33=pB[33];
  remap2<1,0,2,3>(A, B, slab, lane);
  RY2(6,uA28,uB28) RY2(7,uA29,uB29)
  CX2(7,6,uA30,uB30) CX2(8,7,uA31,uB31) CX2(9,8,uA32,uB32) CX2(4,9,uA33,uB33)
  float2 uA34=pA[34],uA35=pA[35],uA36=pA[36],uA37=pA[37];
  float2 uB34=pB[34],uB35=pB[35],uB36=pB[36],uB37=pB[37];
  remap2<4,5,1,0>(A, B, slab, lane);
  CX2(7,6,uA34,uB34) CX2(8,7,uA35,uB35) CX2(9,8,uA36,uB36) CX2(2,9,uA37,uB37)
  float2 uA38=pA[38],uA39=pA[39];
  float2 uB38=pB[38],uB39=pB[39];
  remap2<2,3,4,5>(A, B, slab, lane);
  CX2(7,6,uA38,uB38) CX2(8,7,uA39,uB39)
#undef RY2
#undef CX2
}

__device__ __forceinline__ int p8_lane_canon(int lane) {
  return (((lane >> 1) & 1) << 9) | ((lane & 1) << 8) | (((lane >> 2) & 1) << 7)
       | (((lane >> 3) & 1) << 6) | (((lane >> 4) & 1) << 5) | (((lane >> 5) & 1) << 4);
}

// product state in P2 layout from one cs row (10 RYs applied to |0>)
__device__ __forceinline__ void product_init(v2f (&a)[16],
    const float2* __restrict__ csrow, int lane) {
  float2 f5 = csrow[5], f4 = csrow[4], f6 = csrow[6], f7 = csrow[7];
  float2 f2 = csrow[2], f3 = csrow[3];
  float2 f8 = csrow[8], f9 = csrow[9], f0 = csrow[0], f1 = csrow[1];
  float lp = ((lane & 1) ? f5.y : f5.x);
  lp *= ((lane & 2) ? f4.y : f4.x);
  lp *= ((lane & 4) ? f6.y : f6.x);
  lp *= ((lane & 8) ? f7.y : f7.x);
  lp *= ((lane & 16) ? f2.y : f2.x);
  lp *= ((lane & 32) ? f3.y : f3.x);
#pragma unroll
  for (int r = 0; r < 16; ++r) {
    float rp = ((r & 1) ? f8.y : f8.x) * ((r & 2) ? f9.y : f9.x)
             * ((r & 4) ? f0.y : f0.x) * ((r & 8) ? f1.y : f1.x);
    a[r].x = lp * rp;
    a[r].y = 0.f;
  }
}

// ------------------------- params: register-tiled GEMM ----------------------
__global__ __launch_bounds__(256) void params_kernel(
    const float* __restrict__ emb, const float* __restrict__ W,
    const float* __restrict__ bias,
    const float* __restrict__ lcu_re, const float* __restrict__ lcu_im,
    const float* __restrict__ ffp,
    float2* __restrict__ cs, float2* __restrict__ ffcs, float2* __restrict__ lcu) {
  int blk = blockIdx.x;
  int tid = threadIdx.x;
  if (blk == 256) {
    if (tid < NPQC) {
      float h = 0.5f * ffp[tid];
      ffcs[tid] = make_float2(cosf(h), sinf(h));
    }
    if (tid == 64) {
      float ssum = 0.f;
      for (int i = 0; i < NT; ++i) {
        float re = lcu_re[i], im = lcu_im[i];
        ssum += sqrtf(re * re + im * im);
      }
      float inv = 1.f / ssum;
      for (int i = 0; i < NT; ++i)
        lcu[i] = make_float2(lcu_re[i] * inv, lcu_im[i] * inv);
    }
    return;
  }

  __shared__ float Asl[16 * 516];   // 33 KB; reused as reduction buffer
  int row0 = blk * 16;

  const float4* eg = (const float4*)(emb + (size_t)row0 * DM);
#pragma unroll
  for (int i = 0; i < 8; ++i) {
    int e = tid + i * 256;
    int r = e >> 7, k4 = e & 127;
    float4 v = eg[e];
    *(float4*)&Asl[r * 516 + k4 * 4] = v;
  }
  __syncthreads();

  int kq = tid >> 6;
  int lane = tid & 63;
  int rg = lane >> 3;
  int cg = lane & 7;

  const float* Ar0 = &Asl[(2 * rg) * 516 + kq * 128];
  const float* Ar1 = Ar0 + 516;
  const float* Bg  = W + (size_t)(5 * cg) * DM + kq * 128;

  float acc[2][5] = {};
#pragma unroll 4
  for (int k = 0; k < 128; k += 4) {
    float4 a0 = *(const float4*)(Ar0 + k);
    float4 a1 = *(const float4*)(Ar1 + k);
#pragma unroll
    for (int j = 0; j < 5; ++j) {
      float4 b = *(const float4*)(Bg + j * DM + k);
      acc[0][j] += a0.x * b.x + a0.y * b.y + a0.z * b.z + a0.w * b.w;
      acc[1][j] += a1.x * b.x + a1.y * b.y + a1.z * b.z + a1.w * b.w;
    }
  }

  __syncthreads();
  float* red = Asl;
#pragma unroll
  for (int i = 0; i < 2; ++i)
#pragma unroll
    for (int j = 0; j < 5; ++j)
      red[kq * 644 + (2 * rg + i) * 40 + 5 * cg + j] = acc[i][j];
  __syncthreads();

  for (int o = tid; o < 640; o += 256) {
    float v = bias[o % 40] + red[o] + red[644 + o] + red[1288 + o] + red[1932 + o];
    float h = 0.5f * v;
    cs[(size_t)blk * 640 + o] = make_float2(cosf(h), sinf(h));
  }
}

// ------------------------- QSVT step (dual-token waves) --------------------
// grid = 1024 x 128 thr (2 waves). block = (b = blk>>3, slice qq = blk&7);
// wave wvu handles tokens l0 = qq*4 + 2*wvu and l0+1 in ONE pass.
template<bool FIRST>
__global__ __launch_bounds__(128, 2) void pqc_step(
    const float2* __restrict__ cs, const float2* __restrict__ lcu,
    const v2f* __restrict__ src, v2f* __restrict__ dst) {
  __shared__ v4f slabs[2][1024];   // 32 KB
  int lane = threadIdx.x & 63;
  int wvu = __builtin_amdgcn_readfirstlane(threadIdx.x >> 6);
  int blk = blockIdx.x;
  int b = blk >> 3, qq = blk & 7;
  int l0 = qq * 4 + 2 * wvu;
  const float2* csA = cs + (size_t)(b * NT + l0) * NPQC;
  const float2* csB = csA + NPQC;
  v4f* slab = slabs[wvu];

  v2f A[16], Bs[16];
  if constexpr (FIRST) {
    product_init(A, csA, lane);
    product_init(Bs, csB, lane);
  } else {
    const v2f* s = src + (size_t)b * DIM;
#pragma unroll
    for (int r = 0; r < 16; ++r) {
      int n = r * 64 + lane;
      v2f acc = (v2f)(0.f);
#pragma unroll
      for (int q = 0; q < 8; ++q) acc += s[n + q * PSTRIDE];
      A[r] = acc;
      Bs[r] = acc;      // same input state for both tokens
    }
  }

  apply_pqc2<FIRST>(A, Bs, csA, csB, slab, lane);

  // weighted combine of both tokens -> own slab (canonical swizzled, v2f view)
  float2 wA = lcu[l0], wB = lcu[l0 + 1];
  v2f* slab2 = (v2f*)slabs[wvu];
  int pl = p8_lane_canon(lane);
  pl ^= (pl >> 5);
#pragma unroll
  for (int r = 0; r < 16; ++r) {
    int rc = ((r & 1) << 3) | ((r & 2) << 1) | ((r & 4) >> 1) | ((r & 8) >> 3); // rev4
    slab2[pl ^ rc] = wA.x * A[r] + wA.y * Jc(A[r])
                   + wB.x * Bs[r] + wB.y * Jc(Bs[r]);
  }
  __syncthreads();

  // reduce 2 wave-partials -> global partial slice (canonical layout)
  v2f* s0 = (v2f*)slabs[0];
  v2f* s1 = (v2f*)slabs[1];
  v2f* dst_b = dst + (size_t)(qq * BATCH + b) * DIM;
#pragma unroll
  for (int i = 0; i < 8; ++i) {
    int n = threadIdx.x + i * 128;
    int ph = n ^ (n >> 5);
    dst_b[n] = s0[ph] + s1[ph];
  }
}

// ------------------------- final -------------------------------------------
// 32 blocks x 4 waves (wave = one batch element). Measurement reductions via
// LDS transpose: 30 per-lane partials -> stride-65 LDS -> 30 lanes sum 64.
__global__ __launch_bounds__(256, 2) void final_kernel(
    const v2f* __restrict__ part1, const v2f* __restrict__ part2,
    const float* __restrict__ qsvt, const float2* __restrict__ ffcs,
    float* __restrict__ out) {
  __shared__ v2f slabs[4][1024];   // 32 KB
  int lane = threadIdx.x & 63;
  int wvu = __builtin_amdgcn_readfirstlane(threadIdx.x >> 6);
  int b = blockIdx.x * 4 + wvu;
  float q0 = qsvt[0], q1 = qsvt[1], q2 = qsvt[2];

  v2f a[16];
  const v2f* p1 = part1 + (size_t)b * DIM;
  const v2f* p2 = part2 + (size_t)b * DIM;
#pragma unroll
  for (int r = 0; r < 16; ++r) {
    int n = r * 64 + lane;
    v2f m1 = (v2f)(0.f), m2 = (v2f)(0.f);
#pragma unroll
    for (int q = 0; q < 8; ++q) {
      m1 += p1[n + q * PSTRIDE];
      m2 += p2[n + q * PSTRIDE];
    }
    a[r] = q1 * m1 + q2 * m2;
  }
  if (lane == 0) a[0].x += q0;

  float nn = 0.f;
#pragma unroll
  for (int r = 0; r < 16; ++r) nn += a[r].x * a[r].x + a[r].y * a[r].y;
#pragma unroll
  for (int o = 1; o < 64; o <<= 1) nn += __shfl_xor(nn, o);
  float inv = 1.f / sqrtf(nn);
#pragma unroll
  for (int r = 0; r < 16; ++r) a[r] *= inv;

  apply_pqc_phased(a, ffcs, slabs[wvu], lane);

  // per-lane partials: prt[w]=X, prt[10+w]=Y, prt[20+w]=Z  (P8 layout)
  constexpr int BPOS[10] = {1, 0, 2, 3, 4, 5, 6, 7, 8, 9};
  float prt[30];
#pragma unroll
  for (int w = 0; w < NQ; ++w) {
    const int p = BPOS[w];
    float xr = 0.f, xi = 0.f, zz = 0.f;
    if (p >= 6) {
      const int m = 1 << (p - 6);
#pragma unroll
      for (int r = 0; r < 16; ++r) {
        float mag = a[r].x * a[r].x + a[r].y * a[r].y;
        zz += (r & m) ? -mag : mag;
        if (!(r & m)) {
          int r1 = r | m;
          xr += a[r].x * a[r1].x + a[r].y * a[r1].y;
          xi += a[r].x * a[r1].y - a[r].y * a[r1].x;
        }
      }
    } else {
      const int lm = 1 << p;
      bool lo = !(lane & lm);
#pragma unroll
      for (int r = 0; r < 16; ++r) {
        float mag = a[r].x * a[r].x + a[r].y * a[r].y;
        zz += lo ? mag : -mag;
        float pr = __shfl_xor(a[r].x, lm);
        float pi = __shfl_xor(a[r].y, lm);
        if (lo) {
          xr += a[r].x * pr + a[r].y * pi;
          xi += a[r].x * pi - a[r].y * pr;
        }
      }
    }
    prt[w]      = xr;
    prt[10 + w] = xi;
    prt[20 + w] = zz;
  }

  // LDS transpose reduce: stride 65 -> conflict-free rows; slab is free now.
  float* tb = (float*)slabs[wvu];   // 2048 floats
#pragma unroll
  for (int v = 0; v < 30; ++v) tb[v * 65 + lane] = prt[v];
  asm volatile("s_waitcnt lgkmcnt(0)" ::: "memory");
  if (lane < 30) {
    float s = 0.f;
#pragma unroll
    for (int k = 0; k < 64; ++k) s += tb[lane * 65 + k];
    float sc = (lane < 20) ? 2.f : 1.f;
    out[b * 30 + lane] = sc * s;
  }
}

// ------------------------- launch ------------------------------------------

extern "C" void kernel_launch(void* const* d_in, const int* in_sizes, int n_in,
                              void* d_out, int out_size, void* d_ws, size_t ws_size,
                              hipStream_t stream) {
  const float* emb    = (const float*)d_in[0];
  const float* W      = (const float*)d_in[1];
  const float* bias   = (const float*)d_in[2];
  const float* lcu_re = (const float*)d_in[3];
  const float* lcu_im = (const float*)d_in[4];
  const float* qsvt   = (const float*)d_in[5];
  const float* ffp    = (const float*)d_in[6];
  float* out = (float*)d_out;

  char* ws = (char*)d_ws;
  // cs[4096][40] f2 | ffcs[40] | lcu[32] | pad |
  // part1[8][128][1024] v2f (8 MB) | part2[8][128][1024] v2f (8 MB)
  float2* cs    = (float2*)ws;                               // 1,310,720 B
  float2* ffcs  = (float2*)(ws + 1310720);                   //       320 B
  float2* lcu   = (float2*)(ws + 1311040);                   //       256 B
  v2f*    part1 = (v2f*)(ws + 1311744);                      // 8,388,608 B
  v2f*    part2 = (v2f*)(ws + 1311744 + 8388608);            // 8,388,608 B

  params_kernel<<<257, 256, 0, stream>>>(emb, W, bias, lcu_re, lcu_im, ffp,
                                         cs, ffcs, lcu);
  pqc_step<true><<<1024, 128, 0, stream>>>(cs, lcu, nullptr, part1);
  pqc_step<false><<<1024, 128, 0, stream>>>(cs, lcu, part1, part2);
  final_kernel<<<BATCH / 4, 256, 0, stream>>>(part1, part2, qsvt, ffcs, out);
}